// Round 5
// baseline (330.254 us; speedup 1.0000x reference)
//
#include <hip/hip_runtime.h>

#define B_ 4
#define T_ 2048
#define C_ 1024
#define H_ 16
#define D_ 64

typedef __attribute__((ext_vector_type(8))) short short8;
typedef __attribute__((ext_vector_type(4))) float f32x4;

// float -> bf16 with round-to-nearest-even (fallback path)
__device__ inline unsigned short f2bf(float f) {
    union { float f; unsigned u; } v; v.f = f;
    unsigned r = v.u + 0x7fffu + ((v.u >> 16) & 1u);
    return (unsigned short)(r >> 16);
}

// pack two fp32 -> packed bf16x2 (hardware v_cvt_pk_bf16_f32 on gfx950)
__device__ inline unsigned int pk_bf16(float a, float b) {
#if __has_builtin(__builtin_amdgcn_cvt_pk_bf16_f32)
    typedef __attribute__((ext_vector_type(2))) __bf16 bf16x2;
    bf16x2 v = __builtin_amdgcn_cvt_pk_bf16_f32(a, b);
    return __builtin_bit_cast(unsigned int, v);
#else
    return (unsigned)f2bf(a) | ((unsigned)f2bf(b) << 16);
#endif
}

// 16-lane max reduce in pure VALU via DPP
__device__ inline float dpp_max16(float x) {
    int t;
    t = __builtin_amdgcn_update_dpp(0, __builtin_bit_cast(int, x), 0xB1, 0xF, 0xF, true);
    x = fmaxf(x, __builtin_bit_cast(float, t));
    t = __builtin_amdgcn_update_dpp(0, __builtin_bit_cast(int, x), 0x4E, 0xF, 0xF, true);
    x = fmaxf(x, __builtin_bit_cast(float, t));
    t = __builtin_amdgcn_update_dpp(0, __builtin_bit_cast(int, x), 0x141, 0xF, 0xF, true);
    x = fmaxf(x, __builtin_bit_cast(float, t));
    t = __builtin_amdgcn_update_dpp(0, __builtin_bit_cast(int, x), 0x140, 0xF, 0xF, true);
    x = fmaxf(x, __builtin_bit_cast(float, t));
    return x;
}

// async 16B global -> LDS (wave-uniform LDS base + lane*16)
__device__ inline void async_ld16(const void* g, void* lds) {
    __builtin_amdgcn_global_load_lds(
        (const __attribute__((address_space(1))) unsigned int*)g,
        (__attribute__((address_space(3))) unsigned int*)lds, 16, 0, 0);
}

// ---------------------------------------------------------------------------
// fp32 -> bf16 flat convert (n multiple of 4)
// ---------------------------------------------------------------------------
__global__ __launch_bounds__(256) void convert_bf16(
    const float* __restrict__ src, unsigned short* __restrict__ dst, int n)
{
    int i = (blockIdx.x * 256 + threadIdx.x) * 4;
    if (i >= n) return;
    float4 v = *(const float4*)(src + i);
    uint2 o;
    o.x = pk_bf16(v.x, v.y);
    o.y = pk_bf16(v.z, v.w);
    *(uint2*)(dst + i) = o;
}

// ---------------------------------------------------------------------------
// Merged weight prep: w_qkv[1024][3072] -> wqkvT[3072][1024] bf16 and
// w_proj[1024][1024] -> wprojT[1024][1024] bf16. 32x32 LDS tiles.
// ---------------------------------------------------------------------------
__global__ __launch_bounds__(256) void prep_weights(
    const float* __restrict__ w_qkv, const float* __restrict__ w_proj,
    unsigned short* __restrict__ wqkvT, unsigned short* __restrict__ wprojT)
{
    __shared__ float tile[32][33];
    int bx = blockIdx.x;
    const int by = blockIdx.y;
    const float* src; unsigned short* dst; int Cc;
    if (bx < 96) { src = w_qkv; dst = wqkvT; Cc = 3072; }
    else         { src = w_proj; dst = wprojT; Cc = 1024; bx -= 96; }
    const int R = 1024;
    const int tx = threadIdx.x & 31, ty = threadIdx.x >> 5;
    #pragma unroll
    for (int r = 0; r < 32; r += 8)
        tile[ty + r][tx] = src[(size_t)(by*32 + ty + r) * Cc + bx*32 + tx];
    __syncthreads();
    #pragma unroll
    for (int r = 0; r < 32; r += 8)
        dst[(size_t)(bx*32 + ty + r) * R + by*32 + tx] = f2bf(tile[tx][ty + r]);
}

// ---------------------------------------------------------------------------
// QKV GEMM, m97 structure: 128x128 tile, BK=32, global_load_lds(16B).
// q/k: swapped MFMA operands -> 4 consecutive d per lane -> packed 8B stores.
// v: normal orientation, epilogue transposes through LDS (aliased onto the
//    dead As/Bs staging buffer) -> fully coalesced uint4 stores to [B,H,D,T].
// q scaled by D^-0.5 * log2(e) (exp2-domain softmax downstream).
// ---------------------------------------------------------------------------
__global__ __launch_bounds__(256) void gemm_qkv(
    const unsigned short* __restrict__ A,   // [8192][1024] bf16
    const unsigned short* __restrict__ BT,  // [3072][1024] bf16
    const float* __restrict__ bias,         // [3072] fp32
    unsigned short* __restrict__ qb, unsigned short* __restrict__ kb,
    unsigned short* __restrict__ vtb)
{
    __shared__ unsigned short SM[8704];     // As(4096) + Bs(4096) | VST 64x136
    unsigned short* const As = SM;
    unsigned short* const Bs = SM + 4096;
    const int tid = threadIdx.x;
    const int wave = tid >> 6, lane = tid & 63;
    const int wm = wave >> 1, wn = wave & 1;
    const int l15 = lane & 15, lq = lane >> 4;
    const int m0 = blockIdx.y * 128, n0 = blockIdx.x * 128;
    const int srow = tid >> 2, sg = tid & 3;
    const int sel = n0 >> 10;   // 0=q 1=k 2=v (block-uniform)

    f32x4 acc[4][4] = {};

    for (int k0 = 0; k0 < 1024; k0 += 32) {
        async_ld16(A  + (size_t)(m0 + srow)      * 1024 + k0 + sg*8, (char*)As + wave*1024);
        async_ld16(A  + (size_t)(m0 + 64 + srow) * 1024 + k0 + sg*8, (char*)As + 4096 + wave*1024);
        async_ld16(BT + (size_t)(n0 + srow)      * 1024 + k0 + sg*8, (char*)Bs + wave*1024);
        async_ld16(BT + (size_t)(n0 + 64 + srow) * 1024 + k0 + sg*8, (char*)Bs + 4096 + wave*1024);
        __syncthreads();
        short8 af[4], bf[4];
        #pragma unroll
        for (int i = 0; i < 4; ++i) {
            af[i] = *(const short8*)&As[(wm*64 + i*16 + l15) * 32 + lq*8];
            bf[i] = *(const short8*)&Bs[(wn*64 + i*16 + l15) * 32 + lq*8];
        }
        if (sel < 2) {
            #pragma unroll
            for (int mi = 0; mi < 4; ++mi)
                #pragma unroll
                for (int ni = 0; ni < 4; ++ni)
                    acc[mi][ni] = __builtin_amdgcn_mfma_f32_16x16x32_bf16(
                        bf[ni], af[mi], acc[mi][ni], 0, 0, 0);  // D[n][m]
        } else {
            #pragma unroll
            for (int mi = 0; mi < 4; ++mi)
                #pragma unroll
                for (int ni = 0; ni < 4; ++ni)
                    acc[mi][ni] = __builtin_amdgcn_mfma_f32_16x16x32_bf16(
                        af[mi], bf[ni], acc[mi][ni], 0, 0, 0);  // D[m][n]
        }
        __syncthreads();
    }

    if (sel < 2) {
        // lane l15 -> t; reg r -> d. 4 consecutive d per lane -> 8B store.
        const float qs = (sel == 0) ? 0.180336880f : 1.0f;  // 0.125*log2(e) | 1
        unsigned short* dst = (sel == 0) ? qb : kb;
        #pragma unroll
        for (int mi = 0; mi < 4; ++mi) {
            const int t = m0 + wm*64 + mi*16 + l15;
            const int bb = t >> 11, tt = t & 2047;
            #pragma unroll
            for (int ni = 0; ni < 4; ++ni) {
                const int nb = n0 + wn*64 + ni*16 + lq*4;
                const int hh = (nb >> 6) & 15, d0 = nb & 63;
                float4 bv = *(const float4*)(bias + nb);
                float v0 = (acc[mi][ni][0] + bv.x) * qs;
                float v1 = (acc[mi][ni][1] + bv.y) * qs;
                float v2 = (acc[mi][ni][2] + bv.z) * qs;
                float v3 = (acc[mi][ni][3] + bv.w) * qs;
                uint2 pk; pk.x = pk_bf16(v0, v1); pk.y = pk_bf16(v2, v3);
                *(uint2*)(dst + ((size_t)(bb*16 + hh)*2048 + tt)*64 + d0) = pk;
            }
        }
    } else {
        // v: two heads per block (wn). Transpose each 64d x 128t tile via LDS,
        // then coalesced 16B stores. VST aliases As/Bs (dead after k-loop).
        unsigned short* const VST = SM;     // [64][136]
        const int bb = m0 >> 11, t0 = m0 & 2047;
        const int hbase = (n0 & 1023) >> 6;
        #pragma unroll 1
        for (int ph = 0; ph < 2; ++ph) {
            if (wn == ph) {
                #pragma unroll
                for (int ni = 0; ni < 4; ++ni) {
                    const int d = ni*16 + l15;
                    const float bs = bias[n0 + wn*64 + ni*16 + l15];
                    #pragma unroll
                    for (int mi = 0; mi < 4; ++mi) {
                        const int trel = wm*64 + mi*16 + lq*4;
                        uint2 pk;
                        pk.x = pk_bf16(acc[mi][ni][0] + bs, acc[mi][ni][1] + bs);
                        pk.y = pk_bf16(acc[mi][ni][2] + bs, acc[mi][ni][3] + bs);
                        *(uint2*)&VST[d*136 + trel] = pk;
                    }
                }
            }
            __syncthreads();
            {
                const int d = tid >> 2, c = (tid & 3) * 32;
                const int hh = hbase + ph;
                unsigned short* dst = vtb + ((size_t)(bb*16 + hh)*64 + d)*2048 + t0 + c;
                uint4 w0 = *(const uint4*)&VST[d*136 + c];
                uint4 w1 = *(const uint4*)&VST[d*136 + c + 8];
                uint4 w2 = *(const uint4*)&VST[d*136 + c + 16];
                uint4 w3 = *(const uint4*)&VST[d*136 + c + 24];
                *(uint4*)(dst)      = w0;
                *(uint4*)(dst + 8)  = w1;
                *(uint4*)(dst + 16) = w2;
                *(uint4*)(dst + 24) = w3;
            }
            __syncthreads();
        }
    }
}

// ---------------------------------------------------------------------------
// Output projection GEMM (swapped operands -> float4 coalesced stores):
// ab[8192][1024] bf16 @ wprojT[1024][1024] bf16 + bias -> out fp32
// ---------------------------------------------------------------------------
__global__ __launch_bounds__(256) void gemm_proj(
    const unsigned short* __restrict__ A,   // [8192][1024] bf16
    const unsigned short* __restrict__ BT,  // [1024][1024] bf16
    const float* __restrict__ bias,         // [1024]
    float* __restrict__ out)
{
    __shared__ unsigned short As[128 * 32];
    __shared__ unsigned short Bs[128 * 32];
    const int tid = threadIdx.x;
    const int wave = tid >> 6, lane = tid & 63;
    const int wm = wave >> 1, wn = wave & 1;
    const int l15 = lane & 15, lq = lane >> 4;
    const int m0 = blockIdx.y * 128, n0 = blockIdx.x * 128;
    const int srow = tid >> 2, sg = tid & 3;

    f32x4 acc[4][4] = {};

    for (int k0 = 0; k0 < 1024; k0 += 32) {
        async_ld16(A  + (size_t)(m0 + srow)      * 1024 + k0 + sg*8, (char*)As + wave*1024);
        async_ld16(A  + (size_t)(m0 + 64 + srow) * 1024 + k0 + sg*8, (char*)As + 4096 + wave*1024);
        async_ld16(BT + (size_t)(n0 + srow)      * 1024 + k0 + sg*8, (char*)Bs + wave*1024);
        async_ld16(BT + (size_t)(n0 + 64 + srow) * 1024 + k0 + sg*8, (char*)Bs + 4096 + wave*1024);
        __syncthreads();
        short8 af[4], bf[4];
        #pragma unroll
        for (int i = 0; i < 4; ++i) {
            af[i] = *(const short8*)&As[(wm*64 + i*16 + l15) * 32 + lq*8];
            bf[i] = *(const short8*)&Bs[(wn*64 + i*16 + l15) * 32 + lq*8];
        }
        #pragma unroll
        for (int mi = 0; mi < 4; ++mi)
            #pragma unroll
            for (int ni = 0; ni < 4; ++ni)
                acc[mi][ni] = __builtin_amdgcn_mfma_f32_16x16x32_bf16(
                    bf[ni], af[mi], acc[mi][ni], 0, 0, 0);  // D[n][m]
        __syncthreads();
    }

    #pragma unroll
    for (int mi = 0; mi < 4; ++mi) {
        const int m = m0 + wm*64 + mi*16 + l15;
        #pragma unroll
        for (int ni = 0; ni < 4; ++ni) {
            const int nb = n0 + wn*64 + ni*16 + lq*4;
            float4 bv = *(const float4*)(bias + nb);
            float4 o;
            o.x = acc[mi][ni][0] + bv.x;
            o.y = acc[mi][ni][1] + bv.y;
            o.z = acc[mi][ni][2] + bv.z;
            o.w = acc[mi][ni][3] + bv.w;
            *(float4*)(out + (size_t)m * 1024 + nb) = o;
        }
    }
}

// ---------------------------------------------------------------------------
// MFMA flash attention v4, causal, exp2-domain (q pre-scaled by 0.125*log2e).
// One 64-row q-tile per block; grid 2048 blocks (8/CU queued, 5 resident by
// LDS). Heavy tiles dispatch first (qblk = 31 - idx) so light tiles backfill.
// XCD swizzle: 8 bh per XCD class -> 4 MB K/V working set = one L2.
// DPP max-reduce, l via ones-row MFMA, packed bf16 converts.
// LDS: Ks 9.2K + Vt 11.5K + Ps 9.2K = 29.5KB -> 5 blocks/CU.
// ---------------------------------------------------------------------------
__global__ __launch_bounds__(256, 5) void attn_mfma(
    const unsigned short* __restrict__ qb,   // [B,H,T,D]
    const unsigned short* __restrict__ kb,   // [B,H,T,D]
    const unsigned short* __restrict__ vtb,  // [B,H,D,T]
    unsigned short* __restrict__ ab)         // [B*T][C]
{
    __shared__ unsigned short Ks[64][72];
    __shared__ unsigned short Vt[80][72];   // rows 64..79: row64=1.0, rest 0
    __shared__ unsigned short Ps[64][72];   // Q staging, then P (wave-private rows)

    const int tid  = threadIdx.x;
    const int wave = tid >> 6, lane = tid & 63;
    const int l15  = lane & 15, lq = lane >> 4;
    const int linear = blockIdx.x;
    const int xc  = linear & 7;            // XCD class
    const int idx = linear >> 3;
    const int bh  = xc * 8 + (idx & 7);    // 8 bh per XCD class
    const int qblk = 31 - (idx >> 3);      // heavy q-tiles dispatch first
    const int q0 = qblk * 64;
    const int b = bh >> 4, h = bh & 15;
    const size_t base = (size_t)bh * 2048 * 64;

    // persistent ones/zero rows (staging only rewrites Vt rows 0..63)
    for (int i = tid; i < 16 * 72; i += 256) {
        int r = i / 72, cc = i - r * 72;
        Vt[64 + r][cc] = (r == 0) ? (unsigned short)0x3F80 : (unsigned short)0;
    }
    // stage Q tile
    #pragma unroll
    for (int i = 0; i < 2; ++i) {
        int slot = tid + 256 * i;
        int row = slot >> 3, g = slot & 7;
        *(uint4*)&Ps[row][g*8] = *(const uint4*)(qb + base + (size_t)(q0 + row)*64 + g*8);
    }
    __syncthreads();
    short8 qf[2];
    qf[0] = *(const short8*)&Ps[wave*16 + l15][lq*8];
    qf[1] = *(const short8*)&Ps[wave*16 + l15][32 + lq*8];

    f32x4 o[4] = {}, lac = {};
    float mrow[4] = {-1e30f, -1e30f, -1e30f, -1e30f};

    for (int j0 = 0; j0 <= q0; j0 += 64) {
        __syncthreads();   // all waves done with prev Ks/Vt
        #pragma unroll
        for (int i = 0; i < 2; ++i) {
            int slot = tid + 256 * i;
            int row = slot >> 3, g = slot & 7;
            *(uint4*)&Ks[row][g*8] = *(const uint4*)(kb  + base + (size_t)(j0 + row)*64 + g*8);
            *(uint4*)&Vt[row][g*8] = *(const uint4*)(vtb + base + (size_t)row*2048 + j0 + g*8);
        }
        __syncthreads();

        // S = Q K^T (16 q-rows x 64 keys per wave)
        f32x4 s[4] = {};
        #pragma unroll
        for (int ks = 0; ks < 2; ++ks)
            #pragma unroll
            for (int ni = 0; ni < 4; ++ni) {
                short8 kf = *(const short8*)&Ks[ni*16 + l15][ks*32 + lq*8];
                s[ni] = __builtin_amdgcn_mfma_f32_16x16x32_bf16(qf[ks], kf, s[ni], 0, 0, 0);
            }

        // causal mask — only the diagonal tile
        if (j0 == q0) {
            #pragma unroll
            for (int ni = 0; ni < 4; ++ni) {
                int kc = ni*16 + l15;
                #pragma unroll
                for (int r = 0; r < 4; ++r) {
                    int qr = wave*16 + lq*4 + r;
                    if (kc > qr) s[ni][r] = -1e30f;
                }
            }
        }

        // online softmax (exp2 domain), DPP max-reduce
        float al[4];
        #pragma unroll
        for (int r = 0; r < 4; ++r) {
            float mx = fmaxf(fmaxf(s[0][r], s[1][r]), fmaxf(s[2][r], s[3][r]));
            mx = dpp_max16(mx);
            float mnew = fmaxf(mrow[r], mx);
            al[r] = __builtin_amdgcn_exp2f(mrow[r] - mnew);
            mrow[r] = mnew;
        }
        #pragma unroll
        for (int r = 0; r < 4; ++r) {
            float p0 = __builtin_amdgcn_exp2f(s[0][r] - mrow[r]);
            float p1 = __builtin_amdgcn_exp2f(s[1][r] - mrow[r]);
            float p2 = __builtin_amdgcn_exp2f(s[2][r] - mrow[r]);
            float p3 = __builtin_amdgcn_exp2f(s[3][r] - mrow[r]);
            unsigned pa = pk_bf16(p0, p1), pb = pk_bf16(p2, p3);
            const int row = wave*16 + lq*4 + r;
            Ps[row][l15]      = (unsigned short)pa;
            Ps[row][16 + l15] = (unsigned short)(pa >> 16);
            Ps[row][32 + l15] = (unsigned short)pb;
            Ps[row][48 + l15] = (unsigned short)(pb >> 16);
            o[0][r] *= al[r]; o[1][r] *= al[r];
            o[2][r] *= al[r]; o[3][r] *= al[r];
            lac[r] *= al[r];
        }

        // O += P V ; l via ones-column (wave-private Ps rows, no barrier)
        #pragma unroll
        for (int ks = 0; ks < 2; ++ks) {
            short8 pf = *(const short8*)&Ps[wave*16 + l15][ks*32 + lq*8];
            #pragma unroll
            for (int ni = 0; ni < 4; ++ni) {
                short8 vf = *(const short8*)&Vt[ni*16 + l15][ks*32 + lq*8];
                o[ni] = __builtin_amdgcn_mfma_f32_16x16x32_bf16(pf, vf, o[ni], 0, 0, 0);
            }
            short8 vl = *(const short8*)&Vt[64 + l15][ks*32 + lq*8];
            lac = __builtin_amdgcn_mfma_f32_16x16x32_bf16(pf, vl, lac, 0, 0, 0);
        }
    }

    // epilogue: O/l -> ab (l lives in lanes with l15==0)
    #pragma unroll
    for (int r = 0; r < 4; ++r) {
        float l = __shfl(lac[r], (lane & 48));
        float linv = __builtin_amdgcn_rcpf(l);
        int m = b*2048 + q0 + wave*16 + lq*4 + r;
        unsigned pa = pk_bf16(o[0][r]*linv, o[1][r]*linv);
        unsigned pb = pk_bf16(o[2][r]*linv, o[3][r]*linv);
        unsigned short* p = ab + (size_t)m*1024 + h*64;
        p[l15]      = (unsigned short)pa;
        p[16 + l15] = (unsigned short)(pa >> 16);
        p[32 + l15] = (unsigned short)pb;
        p[48 + l15] = (unsigned short)(pb >> 16);
    }
}

extern "C" void kernel_launch(void* const* d_in, const int* in_sizes, int n_in,
                              void* d_out, int out_size, void* d_ws, size_t ws_size,
                              hipStream_t stream) {
    const float* x      = (const float*)d_in[0];   // [B,T,C]
    const float* w_qkv  = (const float*)d_in[1];   // [C,3C]
    const float* b_qkv  = (const float*)d_in[2];   // [3C]
    const float* w_proj = (const float*)d_in[3];   // [C,C]
    const float* b_proj = (const float*)d_in[4];   // [C]
    float* out = (float*)d_out;                    // [B,T,C] fp32

    unsigned short* xb     = (unsigned short*)d_ws;          // 8192*1024
    unsigned short* wqkvT  = xb + 8388608;                   // 3072*1024
    unsigned short* wprojT = wqkvT + 3145728;                // 1024*1024
    unsigned short* qbuf   = wprojT + 1048576;               // [B,H,T,D]
    unsigned short* kbuf   = qbuf + 8388608;                 // [B,H,T,D]
    unsigned short* vtbuf  = kbuf + 8388608;                 // [B,H,D,T]
    unsigned short* abuf   = vtbuf + 8388608;                // [B*T][C]
    // total: 46,137,344 bf16 elems = 92 MiB

    convert_bf16<<<8192, 256, 0, stream>>>(x, xb, 8388608);
    prep_weights<<<dim3(128, 32), 256, 0, stream>>>(w_qkv, w_proj, wqkvT, wprojT);

    gemm_qkv<<<dim3(24, 64), 256, 0, stream>>>(xb, wqkvT, b_qkv, qbuf, kbuf, vtbuf);
    attn_mfma<<<2048, 256, 0, stream>>>(qbuf, kbuf, vtbuf, abuf);
    gemm_proj<<<dim3(8, 64), 256, 0, stream>>>(abuf, wprojT, b_proj, out);
}

// Round 6
// 266.087 us; speedup vs baseline: 1.2411x; 1.2411x over previous
//
#include <hip/hip_runtime.h>

#define B_ 4
#define T_ 2048
#define C_ 1024
#define H_ 16
#define D_ 64

typedef __attribute__((ext_vector_type(8))) short short8;
typedef __attribute__((ext_vector_type(4))) float f32x4;

// float -> bf16 round-to-nearest-even (fallback)
__device__ inline unsigned short f2bf(float f) {
    union { float f; unsigned u; } v; v.f = f;
    unsigned r = v.u + 0x7fffu + ((v.u >> 16) & 1u);
    return (unsigned short)(r >> 16);
}

// pack two fp32 -> packed bf16x2 (v_cvt_pk_bf16_f32 on gfx950)
__device__ inline unsigned int pk_bf16(float a, float b) {
#if __has_builtin(__builtin_amdgcn_cvt_pk_bf16_f32)
    typedef __attribute__((ext_vector_type(2))) __bf16 bf16x2;
    bf16x2 v = __builtin_amdgcn_cvt_pk_bf16_f32(a, b);
    return __builtin_bit_cast(unsigned int, v);
#else
    return (unsigned)f2bf(a) | ((unsigned)f2bf(b) << 16);
#endif
}

// 16-lane max reduce in pure VALU via DPP
__device__ inline float dpp_max16(float x) {
    int t;
    t = __builtin_amdgcn_update_dpp(0, __builtin_bit_cast(int, x), 0xB1, 0xF, 0xF, true);
    x = fmaxf(x, __builtin_bit_cast(float, t));
    t = __builtin_amdgcn_update_dpp(0, __builtin_bit_cast(int, x), 0x4E, 0xF, 0xF, true);
    x = fmaxf(x, __builtin_bit_cast(float, t));
    t = __builtin_amdgcn_update_dpp(0, __builtin_bit_cast(int, x), 0x141, 0xF, 0xF, true);
    x = fmaxf(x, __builtin_bit_cast(float, t));
    t = __builtin_amdgcn_update_dpp(0, __builtin_bit_cast(int, x), 0x140, 0xF, 0xF, true);
    x = fmaxf(x, __builtin_bit_cast(float, t));
    return x;
}

// async 16B global -> LDS (wave-uniform LDS base + lane*16)
__device__ inline void async_ld16(const void* g, void* lds) {
    __builtin_amdgcn_global_load_lds(
        (const __attribute__((address_space(1))) unsigned int*)g,
        (__attribute__((address_space(3))) unsigned int*)lds, 16, 0, 0);
}

// ---------------------------------------------------------------------------
// Merged prep: bid<8192 -> x fp32->bf16 convert; else 32x32 transpose-convert
// of w_qkv (128 col-tiles) / w_proj (32 col-tiles) into [n][k] bf16.
// ---------------------------------------------------------------------------
__global__ __launch_bounds__(256) void prep_all(
    const float* __restrict__ x, const float* __restrict__ w_qkv,
    const float* __restrict__ w_proj,
    unsigned short* __restrict__ xb, unsigned short* __restrict__ wqkvT,
    unsigned short* __restrict__ wprojT)
{
    const int bid = blockIdx.x;
    if (bid < 8192) {
        int i = (bid * 256 + threadIdx.x) * 4;
        float4 v = *(const float4*)(x + i);
        uint2 o;
        o.x = pk_bf16(v.x, v.y);
        o.y = pk_bf16(v.z, v.w);
        *(uint2*)(xb + i) = o;
        return;
    }
    __shared__ float tile[32][33];
    const int tt = bid - 8192;          // 0..4095
    int bx = tt & 127;                  // col tile
    const int by = tt >> 7;             // row tile (0..31)
    const float* src; unsigned short* dst; int Cc;
    if (bx < 96) { src = w_qkv;  dst = wqkvT;  Cc = 3072; }
    else         { src = w_proj; dst = wprojT; Cc = 1024; bx -= 96; }
    const int tx = threadIdx.x & 31, ty = threadIdx.x >> 5;
    #pragma unroll
    for (int r = 0; r < 32; r += 8)
        tile[ty + r][tx] = src[(size_t)(by*32 + ty + r) * Cc + bx*32 + tx];
    __syncthreads();
    #pragma unroll
    for (int r = 0; r < 32; r += 8)
        dst[(size_t)(bx*32 + ty + r) * 1024 + by*32 + tx] = f2bf(tile[tx][ty + r]);
}

// ---------------------------------------------------------------------------
// QKV GEMM: 128x128 tile, BK=64 as TWO m97-style 32-wide LDS buffers
// (global_load_lds-compatible layout, one barrier pair per 64 K).
// q/k: swapped MFMA operands -> 4 consecutive d per lane -> packed 8B stores.
// v: normal orientation -> packed 8B stores to [B,H,D,T] (R4 scatter; L2
//    merges adjacent t-halves of each line - measured no HBM amplification).
// q scaled by D^-0.5 * log2(e) (exp2-domain softmax downstream).
// ---------------------------------------------------------------------------
__global__ __launch_bounds__(256) void gemm_qkv(
    const unsigned short* __restrict__ A,   // [8192][1024] bf16
    const unsigned short* __restrict__ BT,  // [3072][1024] bf16
    const float* __restrict__ bias,         // [3072] fp32
    unsigned short* __restrict__ qb, unsigned short* __restrict__ kb,
    unsigned short* __restrict__ vtb)
{
    __shared__ unsigned short As0[128 * 32], As1[128 * 32];
    __shared__ unsigned short Bs0[128 * 32], Bs1[128 * 32];
    const int tid = threadIdx.x;
    const int wave = tid >> 6, lane = tid & 63;
    const int wm = wave >> 1, wn = wave & 1;
    const int l15 = lane & 15, lq = lane >> 4;
    const int m0 = blockIdx.y * 128, n0 = blockIdx.x * 128;
    const int srow = tid >> 2, sg = tid & 3;   // 64 rows/round, 4x16B per row
    const int sel = n0 >> 10;                  // 0=q 1=k 2=v (block-uniform)

    f32x4 acc[4][4] = {};

    for (int k0 = 0; k0 < 1024; k0 += 64) {
        #pragma unroll
        for (int r = 0; r < 2; ++r) {
            const size_t ra = (size_t)(m0 + r*64 + srow) * 1024 + k0 + sg*8;
            const size_t rb = (size_t)(n0 + r*64 + srow) * 1024 + k0 + sg*8;
            async_ld16(A  + ra,      (char*)As0 + r*4096 + wave*1024);
            async_ld16(A  + ra + 32, (char*)As1 + r*4096 + wave*1024);
            async_ld16(BT + rb,      (char*)Bs0 + r*4096 + wave*1024);
            async_ld16(BT + rb + 32, (char*)Bs1 + r*4096 + wave*1024);
        }
        __syncthreads();
        #pragma unroll
        for (int ks = 0; ks < 2; ++ks) {
            const unsigned short* Asx = ks ? As1 : As0;
            const unsigned short* Bsx = ks ? Bs1 : Bs0;
            short8 af[4], bf[4];
            #pragma unroll
            for (int i = 0; i < 4; ++i) {
                af[i] = *(const short8*)&Asx[(wm*64 + i*16 + l15) * 32 + lq*8];
                bf[i] = *(const short8*)&Bsx[(wn*64 + i*16 + l15) * 32 + lq*8];
            }
            if (sel < 2) {
                #pragma unroll
                for (int mi = 0; mi < 4; ++mi)
                    #pragma unroll
                    for (int ni = 0; ni < 4; ++ni)
                        acc[mi][ni] = __builtin_amdgcn_mfma_f32_16x16x32_bf16(
                            bf[ni], af[mi], acc[mi][ni], 0, 0, 0);  // D[n][m]
            } else {
                #pragma unroll
                for (int mi = 0; mi < 4; ++mi)
                    #pragma unroll
                    for (int ni = 0; ni < 4; ++ni)
                        acc[mi][ni] = __builtin_amdgcn_mfma_f32_16x16x32_bf16(
                            af[mi], bf[ni], acc[mi][ni], 0, 0, 0);  // D[m][n]
            }
        }
        __syncthreads();
    }

    if (sel < 2) {
        // lane l15 -> t; reg r -> d. 4 consecutive d per lane -> 8B store.
        const float qs = (sel == 0) ? 0.180336880f : 1.0f;  // 0.125*log2(e) | 1
        unsigned short* dst = (sel == 0) ? qb : kb;
        #pragma unroll
        for (int mi = 0; mi < 4; ++mi) {
            const int t = m0 + wm*64 + mi*16 + l15;
            const int bb = t >> 11, tt = t & 2047;
            #pragma unroll
            for (int ni = 0; ni < 4; ++ni) {
                const int nb = n0 + wn*64 + ni*16 + lq*4;
                const int hh = (nb >> 6) & 15, d0 = nb & 63;
                float4 bv = *(const float4*)(bias + nb);
                float v0 = (acc[mi][ni][0] + bv.x) * qs;
                float v1 = (acc[mi][ni][1] + bv.y) * qs;
                float v2 = (acc[mi][ni][2] + bv.z) * qs;
                float v3 = (acc[mi][ni][3] + bv.w) * qs;
                uint2 pk; pk.x = pk_bf16(v0, v1); pk.y = pk_bf16(v2, v3);
                *(uint2*)(dst + ((size_t)(bb*16 + hh)*2048 + tt)*64 + d0) = pk;
            }
        }
    } else {
        // lane l15 -> d; reg r -> t. 4 consecutive t per lane -> 8B store.
        #pragma unroll
        for (int mi = 0; mi < 4; ++mi) {
            const int t0 = m0 + wm*64 + mi*16 + lq*4;
            const int bb = t0 >> 11, tt = t0 & 2047;
            #pragma unroll
            for (int ni = 0; ni < 4; ++ni) {
                const int n = n0 + wn*64 + ni*16 + l15;
                const int hh = (n >> 6) & 15, d = n & 63;
                const float bs = bias[n];
                uint2 pk;
                pk.x = pk_bf16(acc[mi][ni][0] + bs, acc[mi][ni][1] + bs);
                pk.y = pk_bf16(acc[mi][ni][2] + bs, acc[mi][ni][3] + bs);
                *(uint2*)(vtb + ((size_t)(bb*16 + hh)*64 + d)*2048 + tt) = pk;
            }
        }
    }
}

// ---------------------------------------------------------------------------
// Output projection GEMM, BK=64 two-buffer structure, swapped operands ->
// float4 coalesced stores. ab[8192][1024] bf16 @ wprojT + bias -> out fp32.
// ---------------------------------------------------------------------------
__global__ __launch_bounds__(256) void gemm_proj(
    const unsigned short* __restrict__ A,   // [8192][1024] bf16
    const unsigned short* __restrict__ BT,  // [1024][1024] bf16
    const float* __restrict__ bias,         // [1024]
    float* __restrict__ out)
{
    __shared__ unsigned short As0[128 * 32], As1[128 * 32];
    __shared__ unsigned short Bs0[128 * 32], Bs1[128 * 32];
    const int tid = threadIdx.x;
    const int wave = tid >> 6, lane = tid & 63;
    const int wm = wave >> 1, wn = wave & 1;
    const int l15 = lane & 15, lq = lane >> 4;
    const int m0 = blockIdx.y * 128, n0 = blockIdx.x * 128;
    const int srow = tid >> 2, sg = tid & 3;

    f32x4 acc[4][4] = {};

    for (int k0 = 0; k0 < 1024; k0 += 64) {
        #pragma unroll
        for (int r = 0; r < 2; ++r) {
            const size_t ra = (size_t)(m0 + r*64 + srow) * 1024 + k0 + sg*8;
            const size_t rb = (size_t)(n0 + r*64 + srow) * 1024 + k0 + sg*8;
            async_ld16(A  + ra,      (char*)As0 + r*4096 + wave*1024);
            async_ld16(A  + ra + 32, (char*)As1 + r*4096 + wave*1024);
            async_ld16(BT + rb,      (char*)Bs0 + r*4096 + wave*1024);
            async_ld16(BT + rb + 32, (char*)Bs1 + r*4096 + wave*1024);
        }
        __syncthreads();
        #pragma unroll
        for (int ks = 0; ks < 2; ++ks) {
            const unsigned short* Asx = ks ? As1 : As0;
            const unsigned short* Bsx = ks ? Bs1 : Bs0;
            short8 af[4], bf[4];
            #pragma unroll
            for (int i = 0; i < 4; ++i) {
                af[i] = *(const short8*)&Asx[(wm*64 + i*16 + l15) * 32 + lq*8];
                bf[i] = *(const short8*)&Bsx[(wn*64 + i*16 + l15) * 32 + lq*8];
            }
            #pragma unroll
            for (int mi = 0; mi < 4; ++mi)
                #pragma unroll
                for (int ni = 0; ni < 4; ++ni)
                    acc[mi][ni] = __builtin_amdgcn_mfma_f32_16x16x32_bf16(
                        bf[ni], af[mi], acc[mi][ni], 0, 0, 0);  // D[n][m]
        }
        __syncthreads();
    }

    #pragma unroll
    for (int mi = 0; mi < 4; ++mi) {
        const int m = m0 + wm*64 + mi*16 + l15;
        #pragma unroll
        for (int ni = 0; ni < 4; ++ni) {
            const int nb = n0 + wn*64 + ni*16 + lq*4;
            float4 bv = *(const float4*)(bias + nb);
            float4 o;
            o.x = acc[mi][ni][0] + bv.x;
            o.y = acc[mi][ni][1] + bv.y;
            o.z = acc[mi][ni][2] + bv.z;
            o.w = acc[mi][ni][3] + bv.w;
            *(float4*)(out + (size_t)m * 1024 + nb) = o;
        }
    }
}

// ---------------------------------------------------------------------------
// MFMA flash attention v4 (unchanged from R5), causal, exp2-domain.
// One 64-row q-tile per block; 2048 blocks, heavy-first; XCD swizzle;
// DPP max-reduce; l via ones-row MFMA. LDS 29.5KB -> 5 blocks/CU.
// ---------------------------------------------------------------------------
__global__ __launch_bounds__(256, 5) void attn_mfma(
    const unsigned short* __restrict__ qb,   // [B,H,T,D]
    const unsigned short* __restrict__ kb,   // [B,H,T,D]
    const unsigned short* __restrict__ vtb,  // [B,H,D,T]
    unsigned short* __restrict__ ab)         // [B*T][C]
{
    __shared__ unsigned short Ks[64][72];
    __shared__ unsigned short Vt[80][72];   // rows 64..79: row64=1.0, rest 0
    __shared__ unsigned short Ps[64][72];   // Q staging, then P (wave-private rows)

    const int tid  = threadIdx.x;
    const int wave = tid >> 6, lane = tid & 63;
    const int l15  = lane & 15, lq = lane >> 4;
    const int linear = blockIdx.x;
    const int xc  = linear & 7;            // XCD class
    const int idx = linear >> 3;
    const int bh  = xc * 8 + (idx & 7);    // 8 bh per XCD class
    const int qblk = 31 - (idx >> 3);      // heavy q-tiles dispatch first
    const int q0 = qblk * 64;
    const int b = bh >> 4, h = bh & 15;
    const size_t base = (size_t)bh * 2048 * 64;

    for (int i = tid; i < 16 * 72; i += 256) {
        int r = i / 72, cc = i - r * 72;
        Vt[64 + r][cc] = (r == 0) ? (unsigned short)0x3F80 : (unsigned short)0;
    }
    #pragma unroll
    for (int i = 0; i < 2; ++i) {
        int slot = tid + 256 * i;
        int row = slot >> 3, g = slot & 7;
        *(uint4*)&Ps[row][g*8] = *(const uint4*)(qb + base + (size_t)(q0 + row)*64 + g*8);
    }
    __syncthreads();
    short8 qf[2];
    qf[0] = *(const short8*)&Ps[wave*16 + l15][lq*8];
    qf[1] = *(const short8*)&Ps[wave*16 + l15][32 + lq*8];

    f32x4 o[4] = {}, lac = {};
    float mrow[4] = {-1e30f, -1e30f, -1e30f, -1e30f};

    for (int j0 = 0; j0 <= q0; j0 += 64) {
        __syncthreads();
        #pragma unroll
        for (int i = 0; i < 2; ++i) {
            int slot = tid + 256 * i;
            int row = slot >> 3, g = slot & 7;
            *(uint4*)&Ks[row][g*8] = *(const uint4*)(kb  + base + (size_t)(j0 + row)*64 + g*8);
            *(uint4*)&Vt[row][g*8] = *(const uint4*)(vtb + base + (size_t)row*2048 + j0 + g*8);
        }
        __syncthreads();

        f32x4 s[4] = {};
        #pragma unroll
        for (int ks = 0; ks < 2; ++ks)
            #pragma unroll
            for (int ni = 0; ni < 4; ++ni) {
                short8 kf = *(const short8*)&Ks[ni*16 + l15][ks*32 + lq*8];
                s[ni] = __builtin_amdgcn_mfma_f32_16x16x32_bf16(qf[ks], kf, s[ni], 0, 0, 0);
            }

        if (j0 == q0) {
            #pragma unroll
            for (int ni = 0; ni < 4; ++ni) {
                int kc = ni*16 + l15;
                #pragma unroll
                for (int r = 0; r < 4; ++r) {
                    int qr = wave*16 + lq*4 + r;
                    if (kc > qr) s[ni][r] = -1e30f;
                }
            }
        }

        float al[4];
        #pragma unroll
        for (int r = 0; r < 4; ++r) {
            float mx = fmaxf(fmaxf(s[0][r], s[1][r]), fmaxf(s[2][r], s[3][r]));
            mx = dpp_max16(mx);
            float mnew = fmaxf(mrow[r], mx);
            al[r] = __builtin_amdgcn_exp2f(mrow[r] - mnew);
            mrow[r] = mnew;
        }
        #pragma unroll
        for (int r = 0; r < 4; ++r) {
            float p0 = __builtin_amdgcn_exp2f(s[0][r] - mrow[r]);
            float p1 = __builtin_amdgcn_exp2f(s[1][r] - mrow[r]);
            float p2 = __builtin_amdgcn_exp2f(s[2][r] - mrow[r]);
            float p3 = __builtin_amdgcn_exp2f(s[3][r] - mrow[r]);
            unsigned pa = pk_bf16(p0, p1), pb = pk_bf16(p2, p3);
            const int row = wave*16 + lq*4 + r;
            Ps[row][l15]      = (unsigned short)pa;
            Ps[row][16 + l15] = (unsigned short)(pa >> 16);
            Ps[row][32 + l15] = (unsigned short)pb;
            Ps[row][48 + l15] = (unsigned short)(pb >> 16);
            o[0][r] *= al[r]; o[1][r] *= al[r];
            o[2][r] *= al[r]; o[3][r] *= al[r];
            lac[r] *= al[r];
        }

        #pragma unroll
        for (int ks = 0; ks < 2; ++ks) {
            short8 pf = *(const short8*)&Ps[wave*16 + l15][ks*32 + lq*8];
            #pragma unroll
            for (int ni = 0; ni < 4; ++ni) {
                short8 vf = *(const short8*)&Vt[ni*16 + l15][ks*32 + lq*8];
                o[ni] = __builtin_amdgcn_mfma_f32_16x16x32_bf16(pf, vf, o[ni], 0, 0, 0);
            }
            short8 vl = *(const short8*)&Vt[64 + l15][ks*32 + lq*8];
            lac = __builtin_amdgcn_mfma_f32_16x16x32_bf16(pf, vl, lac, 0, 0, 0);
        }
    }

    #pragma unroll
    for (int r = 0; r < 4; ++r) {
        float l = __shfl(lac[r], (lane & 48));
        float linv = __builtin_amdgcn_rcpf(l);
        int m = b*2048 + q0 + wave*16 + lq*4 + r;
        unsigned pa = pk_bf16(o[0][r]*linv, o[1][r]*linv);
        unsigned pb = pk_bf16(o[2][r]*linv, o[3][r]*linv);
        unsigned short* p = ab + (size_t)m*1024 + h*64;
        p[l15]      = (unsigned short)pa;
        p[16 + l15] = (unsigned short)(pa >> 16);
        p[32 + l15] = (unsigned short)pb;
        p[48 + l15] = (unsigned short)(pb >> 16);
    }
}

extern "C" void kernel_launch(void* const* d_in, const int* in_sizes, int n_in,
                              void* d_out, int out_size, void* d_ws, size_t ws_size,
                              hipStream_t stream) {
    const float* x      = (const float*)d_in[0];   // [B,T,C]
    const float* w_qkv  = (const float*)d_in[1];   // [C,3C]
    const float* b_qkv  = (const float*)d_in[2];   // [3C]
    const float* w_proj = (const float*)d_in[3];   // [C,C]
    const float* b_proj = (const float*)d_in[4];   // [C]
    float* out = (float*)d_out;                    // [B,T,C] fp32

    unsigned short* xb     = (unsigned short*)d_ws;          // 8192*1024
    unsigned short* wqkvT  = xb + 8388608;                   // 3072*1024
    unsigned short* wprojT = wqkvT + 3145728;                // 1024*1024
    unsigned short* qbuf   = wprojT + 1048576;               // [B,H,T,D]
    unsigned short* kbuf   = qbuf + 8388608;                 // [B,H,T,D]
    unsigned short* vtbuf  = kbuf + 8388608;                 // [B,H,D,T]
    unsigned short* abuf   = vtbuf + 8388608;                // [B*T][C]
    // total: 46,137,344 bf16 elems = 92 MiB

    prep_all<<<12288, 256, 0, stream>>>(x, w_qkv, w_proj, xb, wqkvT, wprojT);
    gemm_qkv<<<dim3(24, 64), 256, 0, stream>>>(xb, wqkvT, b_qkv, qbuf, kbuf, vtbuf);
    attn_mfma<<<2048, 256, 0, stream>>>(qbuf, kbuf, vtbuf, abuf);
    gemm_proj<<<dim3(8, 64), 256, 0, stream>>>(abuf, wprojT, b_proj, out);
}